// Round 3
// baseline (160.684 us; speedup 1.0000x reference)
//
#include <hip/hip_runtime.h>
#include <hip/hip_bf16.h>

// Problem constants (from reference): B=64, N=1024, D=8, S=16
#define BB 64
#define NN 1024
#define DD 8
#define SS 16
#define DS 128           // D*S

typedef __attribute__((ext_vector_type(8))) short short8;
typedef __attribute__((ext_vector_type(4))) float floatx4;

static __device__ __forceinline__ unsigned short f2bf(float f) {
    unsigned int u = __float_as_uint(f);
    unsigned int r = (u + 0x7FFFu + ((u >> 16) & 1u)) >> 16;   // RNE
    return (unsigned short)r;
}

// ---------------- Kernel 1: merged prepass (UNCHANGED, verified) ----------------
__global__ void prepass(const float* __restrict__ x, unsigned short* __restrict__ xT,
                        const float* __restrict__ M, unsigned short* __restrict__ Mb) {
    __shared__ float tile[64 * 68];
    const int t = threadIdx.x;

    if (blockIdx.x < 1024) {                 // ---- convert_M part ----
        int i = (blockIdx.x * 256 + t) * 4;
        float4 v = *(const float4*)(M + i);
        unsigned int p0 = (unsigned int)f2bf(v.x) | ((unsigned int)f2bf(v.y) << 16);
        unsigned int p1 = (unsigned int)f2bf(v.z) | ((unsigned int)f2bf(v.w) << 16);
        *(uint2*)(Mb + i) = make_uint2(p0, p1);
        return;
    }

    const int bid = blockIdx.x - 1024;
    const int i0 = (bid & 15) * 64;
    const int c0 = ((bid >> 4) & 1) * 64;
    const int b  = bid >> 5;
    const float* xb = x + (size_t)b * (NN * DS);

#pragma unroll
    for (int jj = 0; jj < 4; ++jj) {
        int il = (t >> 4) + jj * 16;
        int cl = (t & 15) * 4;
        float4 v = *(const float4*)(xb + (size_t)(i0 + il) * DS + c0 + cl);
        *(float4*)(tile + il * 68 + cl) = v;
    }
    __syncthreads();
    int cr  = t >> 2;
    int iq  = (t & 3) * 16;
    int rot = (t & 3) * 2;
    unsigned int p[8];
#pragma unroll
    for (int j = 0; j < 8; ++j) {
        int jp = (j + rot) & 7;
        unsigned short lo = f2bf(tile[(iq + 2 * jp + 0) * 68 + cr]);
        unsigned short hi = f2bf(tile[(iq + 2 * jp + 1) * 68 + cr]);
        p[jp] = (unsigned int)lo | ((unsigned int)hi << 16);
    }
    unsigned short* dst = xT + (size_t)b * (NN * DS) + (size_t)(c0 + cr) * NN + i0 + iq;
    *(uint4*)(dst + 0) = make_uint4(p[0], p[1], p[2], p[3]);
    *(uint4*)(dst + 8) = make_uint4(p[4], p[5], p[6], p[7]);
}

// ---------------- Kernel 2: LDS-free direct-fragment fused GEMM ----------------
// R2 post-mortem: the 128^2 staged loop is LDS-throughput-bound (512 MiB LDS-read
// ~9.8us + 256 MiB L2 ~7.4us + MFMA 6.9us, SERIALIZED by the barrier chain ~26us);
// both deep-pipeline attempts regressed because they added barriers to an LDS-bound
// loop (and R1's 8x2 wave shape raised LDS bytes/FLOP 25%).
// R3: load MFMA fragments DIRECTLY global->VGPR. The 16x16x32 A/B fragment is
// per-lane addressable: lane(kq,lm) reads 16B at row(lm)*2048 + kq*16 + k8*64.
// One wave-load = 16 rows x 64B = 16 fully-consumed cache lines from L2 (Mb 2MiB +
// xT[b] 256KB are XCD-L2-resident; per-XCD set = 4MiB = L2 size; b=blockIdx.x
// fastest pins b%8 to its XCD). No LDS, no glds, ZERO barriers in the K-loop:
// the m97 vmcnt(0)-drain stall is structurally gone; L2/TCP/MFMA overlap via
// 12 waves/CU TLP + full-unroll ILP. Intra-block reuse (wave pairs share A-rows /
// B-cols) is served by L1 (per-step working set ~4KB << 32KB).
// Geometry + acc layout + epilogue are byte-identical to the verified R0 kernel.
__global__ __launch_bounds__(256, 3) void gemm_fused(
    const unsigned short* __restrict__ Mb,   // [N][N] bf16, row o, col i (k-contiguous)
    const unsigned short* __restrict__ xT,   // [B][DS][N] bf16, row ds, col i (k-contiguous)
    const float* __restrict__ w_syn,         // [N][D][S]
    const float* __restrict__ b_dend,        // [N][D]
    const float* __restrict__ w_dend,        // [N][D]
    const float* __restrict__ b_soma,        // [N]
    float* __restrict__ out)                 // [B][N]
{
    __shared__ float ex[128 * 2];            // 1 KB soma exchange (only LDS use)

    const int t      = threadIdx.x;
    const int b      = blockIdx.x;            // b fastest -> XCD = b%8: xT[b]+Mb pinned
    const int o_base = blockIdx.y * 128;

    const int lane = t & 63;
    const int w    = t >> 6;                  // 0..3
    const int wr   = (w >> 1) * 64;           // wave row offset (o)
    const int wc   = (w & 1) * 64;            // wave col offset (ds)
    const int lm   = lane & 15;
    const int kq   = lane >> 4;               // 0..3

    // Per-lane fragment base addresses (16B granule at k-chunk kq within each K=32).
    // A-frag r: rows o_base+wr+r*16+lm ; B-frag c: rows (ds) wc+c*16+lm of xT[b].
    const char* Ar[4];
    const char* Bc[4];
#pragma unroll
    for (int r = 0; r < 4; ++r)
        Ar[r] = (const char*)Mb + ((size_t)(o_base + wr + r * 16 + lm) * NN + kq * 8) * 2;
#pragma unroll
    for (int c = 0; c < 4; ++c)
        Bc[c] = (const char*)xT + ((size_t)b * NN * DS + (size_t)(wc + c * 16 + lm) * NN + kq * 8) * 2;

    floatx4 acc[4][4] = {};

    // K = 1024 = 32 chunks of 32. Fully unrolled: all loads use the 8 lane-base
    // pointers + immediate offsets (k8*64 <= 1984 fits the 13-bit signed imm);
    // compiler interleaves loads/MFMAs with its own counted vmcnt (no barriers).
#pragma unroll
    for (int k8 = 0; k8 < 32; ++k8) {
        const int kb = k8 * 64;               // 32 bf16 = 64 B per chunk
        short8 af[4], bf[4];
#pragma unroll
        for (int r = 0; r < 4; ++r)
            af[r] = *(const short8*)(Ar[r] + kb);
#pragma unroll
        for (int c = 0; c < 4; ++c)
            bf[c] = *(const short8*)(Bc[c] + kb);
#pragma unroll
        for (int r = 0; r < 4; ++r)
#pragma unroll
            for (int c = 0; c < 4; ++c)
                acc[r][c] = __builtin_amdgcn_mfma_f32_16x16x32_bf16(af[r], bf[c], acc[r][c], 0, 0, 0);
    }

    // ---- register epilogue (byte-identical to verified R0) ----
    // C/D layout: acc[r][c][rg]: o = o_base+wr+r*16+kq*4+rg, ds = wc+c*16+lm
    // => dendrite d = (w&1)*4 + c, synapse s = lm. Butterfly over lm (16-lane quad).
    float keep[4];
#pragma unroll
    for (int r = 0; r < 4; ++r) {
#pragma unroll
        for (int rg = 0; rg < 4; ++rg) {
            const int o = o_base + wr + r * 16 + kq * 4 + rg;
#pragma unroll
            for (int c = 0; c < 4; ++c) {
                const int d = (w & 1) * 4 + c;
                float p = acc[r][c][rg] * w_syn[o * DS + d * SS + lm];
                p += __shfl_xor(p, 1);
                p += __shfl_xor(p, 2);
                p += __shfl_xor(p, 4);
                p += __shfl_xor(p, 8);         // all 16 lanes of the quad now hold sum_s
                if (lm == r * 4 + rg) keep[c] = p;
            }
        }
    }
    // each lane finalizes one o: lane lm encodes (r=lm>>2, reg=lm&3)
    {
        const int o_loc = wr + (lm >> 2) * 16 + kq * 4 + (lm & 3);
        const int o     = o_base + o_loc;
        float part = 0.f;
#pragma unroll
        for (int c = 0; c < 4; ++c) {
            const int d = (w & 1) * 4 + c;
            float pre = keep[c] + b_dend[o * DD + d];
            part += tanhf(pre) * w_dend[o * DD + d];
        }
        ex[o_loc * 2 + (w & 1)] = part;        // waves (0,1) cover o 0..63, (2,3) o 64..127
    }
    __syncthreads();
    if (t < 128) {
        float soma = ex[t * 2] + ex[t * 2 + 1] + b_soma[o_base + t];
        out[(size_t)b * NN + o_base + t] = 1.f / (1.f + __expf(-soma));
    }
}

extern "C" void kernel_launch(void* const* d_in, const int* in_sizes, int n_in,
                              void* d_out, int out_size, void* d_ws, size_t ws_size,
                              hipStream_t stream) {
    const float* x      = (const float*)d_in[0];   // [B,N,D,S]
    const float* M      = (const float*)d_in[1];   // [N,N]
    const float* w_syn  = (const float*)d_in[2];   // [N,D,S]
    const float* b_dend = (const float*)d_in[3];   // [N,D]
    const float* w_dend = (const float*)d_in[4];   // [N,D]
    const float* b_soma = (const float*)d_in[5];   // [N]
    float* out = (float*)d_out;

    unsigned short* xT = (unsigned short*)d_ws;                 // [B][DS][N] bf16 : 16 MiB
    unsigned short* Mb = xT + (size_t)BB * NN * DS;             // [N][N]   bf16 :  2 MiB

    prepass   <<<dim3(1024 + 2048), 256, 0, stream>>>(x, xT, M, Mb);
    gemm_fused<<<dim3(BB, NN / 128), 256, 0, stream>>>(Mb, xT, w_syn, b_dend, w_dend, b_soma, out);
}

// Round 4
// 108.316 us; speedup vs baseline: 1.4835x; 1.4835x over previous
//
#include <hip/hip_runtime.h>
#include <hip/hip_bf16.h>

// Problem constants (from reference): B=64, N=1024, D=8, S=16
#define BB 64
#define NN 1024
#define DD 8
#define SS 16
#define DS 128           // D*S

typedef __attribute__((ext_vector_type(8))) short short8;
typedef __attribute__((ext_vector_type(4))) float floatx4;

typedef __attribute__((address_space(1))) const unsigned int glds_src;
typedef __attribute__((address_space(3))) unsigned int glds_dst;

static __device__ __forceinline__ unsigned short f2bf(float f) {
    unsigned int u = __float_as_uint(f);
    unsigned int r = (u + 0x7FFFu + ((u >> 16) & 1u)) >> 16;   // RNE
    return (unsigned short)r;
}

// ---------------- Kernel 1: merged prepass ----------------
// blocks [0,1024): convert matriz_conexao (values exactly 0.0/1.0) fp32 -> bf16
// blocks [1024,3072): x[b][i][ds] fp32 -> xT[b][ds][i] bf16 (k-contiguous GEMM B operand)
__global__ void prepass(const float* __restrict__ x, unsigned short* __restrict__ xT,
                        const float* __restrict__ M, unsigned short* __restrict__ Mb) {
    __shared__ float tile[64 * 68];          // 64x64 fp32 tile, stride 68 (16B-aligned rows)
    const int t = threadIdx.x;

    if (blockIdx.x < 1024) {                 // ---- convert_M part ----
        int i = (blockIdx.x * 256 + t) * 4;
        float4 v = *(const float4*)(M + i);
        unsigned int p0 = (unsigned int)f2bf(v.x) | ((unsigned int)f2bf(v.y) << 16);
        unsigned int p1 = (unsigned int)f2bf(v.z) | ((unsigned int)f2bf(v.w) << 16);
        *(uint2*)(Mb + i) = make_uint2(p0, p1);
        return;
    }

    // ---- transpose part ----
    const int bid = blockIdx.x - 1024;
    const int i0 = (bid & 15) * 64;
    const int c0 = ((bid >> 4) & 1) * 64;
    const int b  = bid >> 5;
    const float* xb = x + (size_t)b * (NN * DS);

#pragma unroll
    for (int jj = 0; jj < 4; ++jj) {
        int il = (t >> 4) + jj * 16;         // 0..63
        int cl = (t & 15) * 4;               // 0..60
        float4 v = *(const float4*)(xb + (size_t)(i0 + il) * DS + c0 + cl);
        *(float4*)(tile + il * 68 + cl) = v;
    }
    __syncthreads();
    int cr  = t >> 2;                        // 0..63 : local ds row
    int iq  = (t & 3) * 16;                  // i sub-offset
    int rot = (t & 3) * 2;                   // j-rotation: breaks the 4-way bank conflict
    unsigned int p[8];
#pragma unroll
    for (int j = 0; j < 8; ++j) {
        int jp = (j + rot) & 7;
        unsigned short lo = f2bf(tile[(iq + 2 * jp + 0) * 68 + cr]);
        unsigned short hi = f2bf(tile[(iq + 2 * jp + 1) * 68 + cr]);
        p[jp] = (unsigned int)lo | ((unsigned int)hi << 16);
    }
    unsigned short* dst = xT + (size_t)b * (NN * DS) + (size_t)(c0 + cr) * NN + i0 + iq;
    *(uint4*)(dst + 0) = make_uint4(p[0], p[1], p[2], p[3]);
    *(uint4*)(dst + 8) = make_uint4(p[4], p[5], p[6], p[7]);
}

// ---------------- Kernel 2: fused GEMM (xm = M @ x_b) + dendrite tanh + soma sigmoid ----------------
// REVERT to the verified best (R0, 108.6/108.5 us sessions). grid = (B, N/128); block 256 (4 waves).
// Tile 128 o x 128 ds, BK=128 (8 iters), single-buffered two-barrier glds loop.
// Plateau ledger (this problem): R1 8-phase port 111.4; R2 counted-vmcnt 115.3;
// R3 LDS-free direct fragments 160.7 (MfmaUtil 7.9% — L2-latency/TA-issue bound:
// per-lane row-stride-2048 fragment loads scatter to 16 lines/wave-load).
// The glds burst + conflict-free b128 LDS reads ARE the efficient operand path;
// with K=1024 (8 kt) the deep-pipeline schedules can't amortize their prologue.
// Per learn_hip m131-m141 this 2-barrier loop doesn't move at HIP source level.
__global__ __launch_bounds__(256, 2) void gemm_fused(
    const unsigned short* __restrict__ Mb,   // [N][N] bf16, row o, col i (k-contiguous)
    const unsigned short* __restrict__ xT,   // [B][DS][N] bf16, row ds, col i (k-contiguous)
    const float* __restrict__ w_syn,         // [N][D][S]
    const float* __restrict__ b_dend,        // [N][D]
    const float* __restrict__ w_dend,        // [N][D]
    const float* __restrict__ b_soma,        // [N]
    float* __restrict__ out)                 // [B][N]
{
    __shared__ __align__(16) unsigned short As[128 * 128];  // 32 KB (o rows, BK=128)
    __shared__ __align__(16) unsigned short Bs[128 * 128];  // 32 KB (ds rows, BK=128)
    __shared__ float ex[128 * 2];                           // 1 KB soma exchange

    const int t      = threadIdx.x;
    const int b      = blockIdx.x;            // b fastest -> XCD = b%8: xT[b] pinned per XCD
    const int o_base = blockIdx.y * 128;

    const char* AgB = (const char*)(Mb + (size_t)o_base * NN);
    const char* BgB = (const char*)(xT + (size_t)b * (NN * DS));

    const int lane = t & 63;
    const int w    = t >> 6;
    const int wr   = (w >> 1) * 64;           // wave row offset (o)
    const int wc   = (w & 1) * 64;            // wave col offset (ds)
    const int lm   = lane & 15;
    const int kq   = lane >> 4;               // 0..3

    // staging: glds j (0..7) of wave w covers rows (w*8+j)*4 + (lane>>4), 16 granules/row.
    // Source granule for LDS slot (lane&15) is (lane&15)^(row&15)  (XOR-16 swizzle).
    int off[8], ldsb[8];
#pragma unroll
    for (int j = 0; j < 8; ++j) {
        const int row = (w * 8 + j) * 4 + (lane >> 4);
        const int sg  = (lane & 15) ^ (row & 15);
        off[j]  = row * (NN * 2) + sg * 16;
        ldsb[j] = (w * 8 + j) * 1024;          // wave-uniform base; +lane*16 is implicit
    }

    floatx4 acc[4][4] = {};

    for (int kt = 0; kt < 8; ++kt) {
        const int kb = kt * 256;               // byte offset along k within a row (BK=128)
        __syncthreads();                       // previous tile's frag reads done
#pragma unroll
        for (int j = 0; j < 8; ++j) {
            __builtin_amdgcn_global_load_lds((glds_src*)(AgB + off[j] + kb),
                                             (glds_dst*)((char*)As + ldsb[j]), 16, 0, 0);
            __builtin_amdgcn_global_load_lds((glds_src*)(BgB + off[j] + kb),
                                             (glds_dst*)((char*)Bs + ldsb[j]), 16, 0, 0);
        }
        __syncthreads();                       // drains vmcnt(0): tile staged
#pragma unroll
        for (int ks = 0; ks < 4; ++ks) {
            short8 af[4], bf[4];
            const int g = (((ks * 4 + kq) ^ lm) * 8);   // swizzled ushort offset in 128-row
#pragma unroll
            for (int r = 0; r < 4; ++r)
                af[r] = *(const short8*)(As + (wr + r * 16 + lm) * 128 + g);
#pragma unroll
            for (int c = 0; c < 4; ++c)
                bf[c] = *(const short8*)(Bs + (wc + c * 16 + lm) * 128 + g);
#pragma unroll
            for (int r = 0; r < 4; ++r)
#pragma unroll
                for (int c = 0; c < 4; ++c)
                    acc[r][c] = __builtin_amdgcn_mfma_f32_16x16x32_bf16(af[r], bf[c], acc[r][c], 0, 0, 0);
        }
    }

    // ---- register epilogue (verified) ----
    // C/D layout: for acc[r][c][reg]: o = o_base+wr+r*16+kq*4+reg, ds = wc+c*16+lm
    // => dendrite d = (w&1)*4 + c, synapse s = lm. Butterfly over lm (within quad-16).
    float keep[4];
#pragma unroll
    for (int r = 0; r < 4; ++r) {
#pragma unroll
        for (int rg = 0; rg < 4; ++rg) {
            const int o = o_base + wr + r * 16 + kq * 4 + rg;
#pragma unroll
            for (int c = 0; c < 4; ++c) {
                const int d = (w & 1) * 4 + c;
                float p = acc[r][c][rg] * w_syn[o * DS + d * SS + lm];
                p += __shfl_xor(p, 1);
                p += __shfl_xor(p, 2);
                p += __shfl_xor(p, 4);
                p += __shfl_xor(p, 8);         // all 16 lanes of the quad now hold sum_s
                if (lm == r * 4 + rg) keep[c] = p;
            }
        }
    }
    // each lane finalizes one o: lane lm encodes (r=lm>>2, reg=lm&3)
    {
        const int o_loc = wr + (lm >> 2) * 16 + kq * 4 + (lm & 3);
        const int o     = o_base + o_loc;
        float part = 0.f;
#pragma unroll
        for (int c = 0; c < 4; ++c) {
            const int d = (w & 1) * 4 + c;
            float pre = keep[c] + b_dend[o * DD + d];
            part += tanhf(pre) * w_dend[o * DD + d];
        }
        ex[o_loc * 2 + (w & 1)] = part;        // waves (0,1) cover o 0..63, (2,3) o 64..127
    }
    __syncthreads();
    if (t < 128) {
        float soma = ex[t * 2] + ex[t * 2 + 1] + b_soma[o_base + t];
        out[(size_t)b * NN + o_base + t] = 1.f / (1.f + __expf(-soma));
    }
}

extern "C" void kernel_launch(void* const* d_in, const int* in_sizes, int n_in,
                              void* d_out, int out_size, void* d_ws, size_t ws_size,
                              hipStream_t stream) {
    const float* x      = (const float*)d_in[0];   // [B,N,D,S]
    const float* M      = (const float*)d_in[1];   // [N,N]
    const float* w_syn  = (const float*)d_in[2];   // [N,D,S]
    const float* b_dend = (const float*)d_in[3];   // [N,D]
    const float* w_dend = (const float*)d_in[4];   // [N,D]
    const float* b_soma = (const float*)d_in[5];   // [N]
    float* out = (float*)d_out;

    unsigned short* xT = (unsigned short*)d_ws;                 // [B][DS][N] bf16 : 16 MiB
    unsigned short* Mb = xT + (size_t)BB * NN * DS;             // [N][N]   bf16 :  2 MiB

    prepass   <<<dim3(1024 + 2048), 256, 0, stream>>>(x, xT, M, Mb);
    gemm_fused<<<dim3(BB, NN / 128), 256, 0, stream>>>(Mb, xT, w_syn, b_dend, w_dend, b_soma, out);
}